// Round 1
// baseline (1458.863 us; speedup 1.0000x reference)
//
#include <hip/hip_runtime.h>
#include <hip/hip_bf16.h>

#define B_SZ 4096
#define FEAT 40960
#define HID  1024
#define L1N  64
#define L2N  32
#define IDX_CAP 512

static __device__ __forceinline__ unsigned short f2bf(float x) {
    __hip_bfloat16 h = __float2bfloat16(x);
    return *reinterpret_cast<unsigned short*>(&h);
}
static __device__ __forceinline__ float bf2f(unsigned short u) {
    unsigned int v = ((unsigned int)u) << 16;
    return __uint_as_float(v);
}
static __device__ __forceinline__ float clipf(float x) {
    return fminf(fmaxf(x, 0.0f), 1.0f);
}

// ---------------------------------------------------------------------------
// Kernel 0: transpose ft_w [HID, FEAT] fp32 -> ft_wT [FEAT, HID] bf16
// ---------------------------------------------------------------------------
__global__ __launch_bounds__(256) void transpose_ftw(
    const float* __restrict__ ftw, unsigned short* __restrict__ ftwT) {
    __shared__ float tile[32][33];
    int tx = threadIdx.x, ty = threadIdx.y;
    int f0 = blockIdx.x * 32;
    int h0 = blockIdx.y * 32;
#pragma unroll
    for (int i = 0; i < 4; ++i) {
        int h = h0 + ty + 8 * i;
        tile[ty + 8 * i][tx] = ftw[(size_t)h * FEAT + f0 + tx];
    }
    __syncthreads();
#pragma unroll
    for (int i = 0; i < 4; ++i) {
        int f = f0 + ty + 8 * i;
        ftwT[(size_t)f * HID + h0 + tx] = f2bf(tile[tx][ty + 8 * i]);
    }
}

// ---------------------------------------------------------------------------
// Kernel 1: per batch row — scan sparse features, gather ft_wT columns,
// stm-select, clip, write h1 [B, 2*HID] bf16
// ---------------------------------------------------------------------------
__global__ __launch_bounds__(256) void ft_kernel(
    const float* __restrict__ wf, const float* __restrict__ bfeat,
    const float* __restrict__ stm, const unsigned short* __restrict__ ftwT,
    const float* __restrict__ ftb, unsigned short* __restrict__ h1) {

    __shared__ int w_idx[IDX_CAP];
    __shared__ int b_idx[IDX_CAP];
    __shared__ int cnt_w, cnt_b;

    const int t = threadIdx.x;
    const int b = blockIdx.x;

    if (t == 0) { cnt_w = 0; cnt_b = 0; }
    __syncthreads();

    // --- scan: 40960 floats per perspective, float4, 40 iters of 256 threads
    const float4* wf4 = (const float4*)(wf + (size_t)b * FEAT);
    const float4* bf4 = (const float4*)(bfeat + (size_t)b * FEAT);
    for (int it = 0; it < (FEAT / 4) / 256; ++it) {
        int i4 = it * 256 + t;
        float4 wv = wf4[i4];
        float4 bv = bf4[i4];
        int base = i4 * 4;
        if (wv.x != 0.f) { int p = atomicAdd(&cnt_w, 1); if (p < IDX_CAP) w_idx[p] = base + 0; }
        if (wv.y != 0.f) { int p = atomicAdd(&cnt_w, 1); if (p < IDX_CAP) w_idx[p] = base + 1; }
        if (wv.z != 0.f) { int p = atomicAdd(&cnt_w, 1); if (p < IDX_CAP) w_idx[p] = base + 2; }
        if (wv.w != 0.f) { int p = atomicAdd(&cnt_w, 1); if (p < IDX_CAP) w_idx[p] = base + 3; }
        if (bv.x != 0.f) { int p = atomicAdd(&cnt_b, 1); if (p < IDX_CAP) b_idx[p] = base + 0; }
        if (bv.y != 0.f) { int p = atomicAdd(&cnt_b, 1); if (p < IDX_CAP) b_idx[p] = base + 1; }
        if (bv.z != 0.f) { int p = atomicAdd(&cnt_b, 1); if (p < IDX_CAP) b_idx[p] = base + 2; }
        if (bv.w != 0.f) { int p = atomicAdd(&cnt_b, 1); if (p < IDX_CAP) b_idx[p] = base + 3; }
    }
    __syncthreads();
    const int nw = min(cnt_w, IDX_CAP);
    const int nb = min(cnt_b, IDX_CAP);

    // --- accumulate: thread t owns h = 4t..4t+3
    float4 bias = ((const float4*)ftb)[t];
    float aw0 = bias.x, aw1 = bias.y, aw2 = bias.z, aw3 = bias.w;
    float ab0 = bias.x, ab1 = bias.y, ab2 = bias.z, ab3 = bias.w;

    for (int i = 0; i < nw; ++i) {
        int f = w_idx[i];
        ushort4 u = ((const ushort4*)(ftwT + (size_t)f * HID))[t];
        aw0 += bf2f(u.x); aw1 += bf2f(u.y); aw2 += bf2f(u.z); aw3 += bf2f(u.w);
    }
    for (int i = 0; i < nb; ++i) {
        int f = b_idx[i];
        ushort4 u = ((const ushort4*)(ftwT + (size_t)f * HID))[t];
        ab0 += bf2f(u.x); ab1 += bf2f(u.y); ab2 += bf2f(u.z); ab3 += bf2f(u.w);
    }

    // --- stm select (stm is exactly 0.0 or 1.0), clip, bf16 store
    const bool wfirst = (stm[b] != 0.0f);
    float f0 = wfirst ? aw0 : ab0, f1 = wfirst ? aw1 : ab1;
    float f2 = wfirst ? aw2 : ab2, f3 = wfirst ? aw3 : ab3;
    float s0 = wfirst ? ab0 : aw0, s1 = wfirst ? ab1 : aw1;
    float s2 = wfirst ? ab2 : aw2, s3 = wfirst ? ab3 : aw3;

    ushort4 of, os;
    of.x = f2bf(clipf(f0)); of.y = f2bf(clipf(f1)); of.z = f2bf(clipf(f2)); of.w = f2bf(clipf(f3));
    os.x = f2bf(clipf(s0)); os.y = f2bf(clipf(s1)); os.z = f2bf(clipf(s2)); os.w = f2bf(clipf(s3));

    ((ushort4*)(h1 + (size_t)b * 2 * HID))[t]       = of;
    ((ushort4*)(h1 + (size_t)b * 2 * HID + HID))[t] = os;
}

// ---------------------------------------------------------------------------
// Kernel 2: back-end MLP. 4 batch rows per block (amortizes l1_w reads).
// h1[2048] -> clip already applied. l1(64)+clip -> l2(32)+clip -> l3(1) -> sigmoid
// ---------------------------------------------------------------------------
__global__ __launch_bounds__(256) void mlp_kernel(
    const unsigned short* __restrict__ h1,
    const float* __restrict__ l1w, const float* __restrict__ l1b,
    const float* __restrict__ l2w, const float* __restrict__ l2b,
    const float* __restrict__ l3w, const float* __restrict__ l3b,
    float* __restrict__ out) {

    const int ROWS = 4;
    __shared__ float  h1s[4][2 * HID];   // 32 KB
    __shared__ float4 part[4 * L1N];     // [p][k] -> rows in .x..w
    __shared__ float  h2s[4][L1N];
    __shared__ float  h3s[4][L2N];

    const int t = threadIdx.x;
    const int r0 = blockIdx.x * ROWS;

    // --- stage h1 rows to LDS (fp32)
    for (int r = 0; r < ROWS; ++r) {
        const ushort4* src = (const ushort4*)(h1 + (size_t)(r0 + r) * 2 * HID);
        ushort4 u0 = src[t];
        ushort4 u1 = src[256 + t];
        h1s[r][4 * t + 0] = bf2f(u0.x); h1s[r][4 * t + 1] = bf2f(u0.y);
        h1s[r][4 * t + 2] = bf2f(u0.z); h1s[r][4 * t + 3] = bf2f(u0.w);
        h1s[r][1024 + 4 * t + 0] = bf2f(u1.x); h1s[r][1024 + 4 * t + 1] = bf2f(u1.y);
        h1s[r][1024 + 4 * t + 2] = bf2f(u1.z); h1s[r][1024 + 4 * t + 3] = bf2f(u1.w);
    }
    __syncthreads();

    // --- l1: k = t&63, p = t>>6 covers 512-wide K slice; wave-uniform p
    {
        const int k = t & 63, p = t >> 6;
        float a0 = 0.f, a1 = 0.f, a2 = 0.f, a3 = 0.f;
        const float4* w4 = (const float4*)(l1w + (size_t)k * 2 * HID + (size_t)p * 512);
        const int jbase = p * 512;
        for (int jj = 0; jj < 128; ++jj) {
            float4 w = w4[jj];
            int j = jbase + jj * 4;
            a0 += w.x * h1s[0][j] + w.y * h1s[0][j + 1] + w.z * h1s[0][j + 2] + w.w * h1s[0][j + 3];
            a1 += w.x * h1s[1][j] + w.y * h1s[1][j + 1] + w.z * h1s[1][j + 2] + w.w * h1s[1][j + 3];
            a2 += w.x * h1s[2][j] + w.y * h1s[2][j + 1] + w.z * h1s[2][j + 2] + w.w * h1s[2][j + 3];
            a3 += w.x * h1s[3][j] + w.y * h1s[3][j + 1] + w.z * h1s[3][j + 2] + w.w * h1s[3][j + 3];
        }
        part[p * L1N + k] = make_float4(a0, a1, a2, a3);
    }
    __syncthreads();
    if (t < L1N) {
        float4 s0 = part[t], s1 = part[L1N + t], s2 = part[2 * L1N + t], s3 = part[3 * L1N + t];
        float bias = l1b[t];
        h2s[0][t] = clipf(s0.x + s1.x + s2.x + s3.x + bias);
        h2s[1][t] = clipf(s0.y + s1.y + s2.y + s3.y + bias);
        h2s[2][t] = clipf(s0.z + s1.z + s2.z + s3.z + bias);
        h2s[3][t] = clipf(s0.w + s1.w + s2.w + s3.w + bias);
    }
    __syncthreads();

    // --- l2: 128 threads, r = t>>5, k = t&31
    if (t < ROWS * L2N) {
        int r = t >> 5, k2 = t & 31;
        float a = l2b[k2];
        for (int j = 0; j < L1N; ++j) a += h2s[r][j] * l2w[k2 * L1N + j];
        h3s[r][k2] = clipf(a);
    }
    __syncthreads();

    // --- l3 + sigmoid
    if (t < ROWS) {
        float raw = l3b[0];
        for (int j = 0; j < L2N; ++j) raw += h3s[t][j] * l3w[j];
        float sig = 1.0f / (1.0f + expf(-raw));
        out[r0 + t] = sig;
        out[B_SZ + r0 + t] = raw;
    }
}

// ---------------------------------------------------------------------------
extern "C" void kernel_launch(void* const* d_in, const int* in_sizes, int n_in,
                              void* d_out, int out_size, void* d_ws, size_t ws_size,
                              hipStream_t stream) {
    const float* wf    = (const float*)d_in[0];
    const float* bfeat = (const float*)d_in[1];
    const float* stm   = (const float*)d_in[2];
    const float* ftw   = (const float*)d_in[3];
    const float* ftb   = (const float*)d_in[4];
    const float* l1w   = (const float*)d_in[5];
    const float* l1b   = (const float*)d_in[6];
    const float* l2w   = (const float*)d_in[7];
    const float* l2b   = (const float*)d_in[8];
    const float* l3w   = (const float*)d_in[9];
    const float* l3b   = (const float*)d_in[10];
    float* out = (float*)d_out;

    // workspace layout: ft_wT bf16 [FEAT*HID] (80 MB), h1 bf16 [B*2*HID] (16 MB)
    unsigned short* ftwT = (unsigned short*)d_ws;
    unsigned short* h1   = ftwT + (size_t)FEAT * HID;

    transpose_ftw<<<dim3(FEAT / 32, HID / 32), dim3(32, 8), 0, stream>>>(ftw, ftwT);
    ft_kernel<<<B_SZ, 256, 0, stream>>>(wf, bfeat, stm, ftwT, ftb, h1);
    mlp_kernel<<<B_SZ / 4, 256, 0, stream>>>(h1, l1w, l1b, l2w, l2b, l3w, l3b, out);
}